// Round 1
// baseline (485.009 us; speedup 1.0000x reference)
//
#include <hip/hip_runtime.h>

// MultiHeadModel: routed MoE (E=8). Compute ONLY the routed expert per sample
// (reference computes dense then selects -> 8x redundant work).
//
// Pipeline (all on `stream`, serialized):
//   s_init    : zero header, perm = -1
//   s_count   : per-expert counts (atomic)
//   s_scan    : padded offsets, row-block -> expert map, nrowblocks
//   s_scatter : perm[slot] = sample  (grouped by expert, 128-row padded)
//   gemm_l1 x2: H = relu(fused @ W1[e] + b1[e])  -> bf16 in ws   (K=2048,N=1024)
//   immune_k  : immune[b] = H1[r] . W2_imm[e] + b2_imm[e]
//   gemm_l2   : gene[b]  = H2[r] @ W2_gene[e] + b2_gene[e]       (K=1024,N=4096)
//   copy_vt   : pass-through vision/text outputs
//
// ws usage: 32 KiB header/perm + 2 x 10 MiB bf16 hidden buffers (~21 MiB).

#define B_N 4096
#define DV  1024
#define DT  1024
#define DD  2048
#define HH  1024
#define GG  4096
#define EE  8
#define BM  128
#define MAXRB 40            // max total row-blocks: 4096/128 + 7 partials <= 39
#define PERM_N (MAXRB * BM) // 5120
#define LDT 40              // LDS tile stride in bf16 elems (80B -> ~2-way banks)

typedef __bf16 bf16x8 __attribute__((ext_vector_type(8)));
typedef float f32x4 __attribute__((ext_vector_type(4)));
typedef unsigned short u16x4v __attribute__((ext_vector_type(4)));
typedef unsigned short u16x8v __attribute__((ext_vector_type(8)));

// hdr int layout: [0..7] counts, [8..15] fill, [16..23] padded offsets,
//                 [24] nrowblocks, [32..95] blk_expert
#define H_CNT 0
#define H_FIL 8
#define H_OFF 16
#define H_NRB 24
#define H_BLK 32

static __device__ __forceinline__ unsigned short f2bf(float f) {
  unsigned u = __builtin_bit_cast(unsigned, f);
  u += 0x7fffu + ((u >> 16) & 1u);   // RNE
  return (unsigned short)(u >> 16);
}
static __device__ __forceinline__ float bf2f(unsigned short s) {
  return __builtin_bit_cast(float, (unsigned)s << 16);
}

__global__ void s_init(int* hdr, int* perm) {
  int i = blockIdx.x * 256 + threadIdx.x;
  if (i < 128) hdr[i] = 0;
  if (i < PERM_N) perm[i] = -1;
}

__global__ void s_count(const int* organ, int* hdr) {
  int b = blockIdx.x * 256 + threadIdx.x;
  if (b < B_N) atomicAdd(&hdr[H_CNT + organ[b]], 1);
}

__global__ void s_scan(int* hdr) {
  if (blockIdx.x == 0 && threadIdx.x == 0) {
    int acc = 0;
    for (int e = 0; e < EE; ++e) {
      hdr[H_OFF + e] = acc;
      int nb = (hdr[H_CNT + e] + BM - 1) >> 7;
      int rb0 = acc >> 7;
      for (int i = 0; i < nb; ++i) hdr[H_BLK + rb0 + i] = e;
      acc += nb << 7;
    }
    hdr[H_NRB] = acc >> 7;
  }
}

__global__ void s_scatter(const int* organ, int* hdr, int* perm) {
  int b = blockIdx.x * 256 + threadIdx.x;
  if (b < B_N) {
    int e = organ[b];
    int slot = hdr[H_OFF + e] + atomicAdd(&hdr[H_FIL + e], 1);
    perm[slot] = b;
  }
}

// ---------------- Layer 1: H = relu(fused @ W1[e] + b1[e]) -> bf16 ----------
__global__ __launch_bounds__(256) void gemm_l1(
    const float* __restrict__ vis, const float* __restrict__ txt,
    const float* __restrict__ W1, const float* __restrict__ b1,
    const int* __restrict__ hdr, const int* __restrict__ perm,
    unsigned short* __restrict__ Hout) {
  const int nrb = hdr[H_NRB];
  const int rb = blockIdx.x;
  if (rb >= nrb) return;
  const int cb = blockIdx.y << 7;           // 8 col-blocks of 128 (N=1024)
  const int e  = hdr[H_BLK + rb];
  const int tid = threadIdx.x;

  __shared__ unsigned short As[BM * LDT];
  __shared__ unsigned short Bs[BM * LDT];

  // A staging: thread -> (row, 16-wide k half)
  const int ar  = tid & 127;
  const int akg = (tid >> 7) << 4;          // 0 or 16
  const int smp = perm[rb * BM + ar];

  // B staging: thread -> (4 cols, 4 ks)
  const int bc = (tid & 31) << 2;           // 0..124
  const int bk = (tid >> 5) << 2;           // 0..28
  const float* Wb = W1 + (size_t)e * DD * HH;

  const int wave = tid >> 6, lane = tid & 63;
  const int wr = (wave >> 1) << 6, wc = (wave & 1) << 6;
  const int lr = lane & 15, lk = (lane >> 4) << 3;

  f32x4 acc[4][4];
#pragma unroll
  for (int m = 0; m < 4; ++m)
#pragma unroll
    for (int n = 0; n < 4; ++n) acc[m][n] = (f32x4){0.f, 0.f, 0.f, 0.f};

  for (int k0 = 0; k0 < DD; k0 += 32) {
    // ---- stage A tile [128][32] (fused row gather, fp32 -> bf16)
    {
      const int kk = k0 + akg;
      u16x8v v0, v1;
      if (smp >= 0) {
        const float* src = (kk < DV) ? (vis + (size_t)smp * DV + kk)
                                     : (txt + (size_t)smp * DT + (kk - DV));
#pragma unroll
        for (int i = 0; i < 2; ++i) {
          float4 f = reinterpret_cast<const float4*>(src)[i];
          v0[4*i+0] = f2bf(f.x); v0[4*i+1] = f2bf(f.y);
          v0[4*i+2] = f2bf(f.z); v0[4*i+3] = f2bf(f.w);
        }
#pragma unroll
        for (int i = 0; i < 2; ++i) {
          float4 f = reinterpret_cast<const float4*>(src)[2 + i];
          v1[4*i+0] = f2bf(f.x); v1[4*i+1] = f2bf(f.y);
          v1[4*i+2] = f2bf(f.z); v1[4*i+3] = f2bf(f.w);
        }
      } else {
#pragma unroll
        for (int i = 0; i < 8; ++i) { v0[i] = 0; v1[i] = 0; }
      }
      *reinterpret_cast<u16x8v*>(&As[ar * LDT + akg])     = v0;
      *reinterpret_cast<u16x8v*>(&As[ar * LDT + akg + 8]) = v1;
    }
    // ---- stage B tile as [col][k] (transpose during write, fp32 -> bf16)
    {
      unsigned short bv[4][4];
#pragma unroll
      for (int i = 0; i < 4; ++i) {
        float4 f = *reinterpret_cast<const float4*>(Wb + (size_t)(k0 + bk + i) * HH + cb + bc);
        bv[0][i] = f2bf(f.x); bv[1][i] = f2bf(f.y);
        bv[2][i] = f2bf(f.z); bv[3][i] = f2bf(f.w);
      }
#pragma unroll
      for (int j = 0; j < 4; ++j) {
        u16x4v w; w[0] = bv[j][0]; w[1] = bv[j][1]; w[2] = bv[j][2]; w[3] = bv[j][3];
        *reinterpret_cast<u16x4v*>(&Bs[(bc + j) * LDT + bk]) = w;
      }
    }
    __syncthreads();
    // ---- compute: 16 MFMA per wave
    bf16x8 af[4], bfr[4];
#pragma unroll
    for (int m = 0; m < 4; ++m)
      af[m] = *reinterpret_cast<const bf16x8*>(&As[(wr + m * 16 + lr) * LDT + lk]);
#pragma unroll
    for (int n = 0; n < 4; ++n)
      bfr[n] = *reinterpret_cast<const bf16x8*>(&Bs[(wc + n * 16 + lr) * LDT + lk]);
#pragma unroll
    for (int m = 0; m < 4; ++m)
#pragma unroll
      for (int n = 0; n < 4; ++n)
        acc[m][n] = __builtin_amdgcn_mfma_f32_16x16x32_bf16(af[m], bfr[n], acc[m][n], 0, 0, 0);
    __syncthreads();
  }

  // ---- epilogue: relu + bias, store bf16 to H
  const int r0 = rb * BM + wr + ((lane >> 4) << 2);
#pragma unroll
  for (int n = 0; n < 4; ++n) {
    const int col = cb + wc + n * 16 + lr;
    const float bias = b1[e * HH + col];
#pragma unroll
    for (int m = 0; m < 4; ++m) {
#pragma unroll
      for (int v = 0; v < 4; ++v) {
        float x = acc[m][n][v] + bias;
        x = x > 0.f ? x : 0.f;
        Hout[(size_t)(r0 + m * 16 + v) * HH + col] = f2bf(x);
      }
    }
  }
}

// ---------------- Layer 2 gene: out[perm[r]] = H2[r] @ W2g[e] + b2g[e] ------
__global__ __launch_bounds__(256) void gemm_l2(
    const unsigned short* __restrict__ H2, const float* __restrict__ W2,
    const float* __restrict__ b2, const int* __restrict__ hdr,
    const int* __restrict__ perm, float* __restrict__ outg) {
  const int nrb = hdr[H_NRB];
  const int rb = blockIdx.x;
  if (rb >= nrb) return;
  const int cb = blockIdx.y << 7;           // 32 col-blocks (N=4096)
  const int e  = hdr[H_BLK + rb];
  const int tid = threadIdx.x;

  __shared__ unsigned short As[BM * LDT];
  __shared__ unsigned short Bs[BM * LDT];

  const int ar  = tid & 127;
  const int akg = (tid >> 7) << 4;
  const unsigned short* Arow = H2 + (size_t)(rb * BM + ar) * HH;

  const int bc = (tid & 31) << 2;
  const int bk = (tid >> 5) << 2;
  const float* Wb = W2 + (size_t)e * HH * GG;

  const int wave = tid >> 6, lane = tid & 63;
  const int wr = (wave >> 1) << 6, wc = (wave & 1) << 6;
  const int lr = lane & 15, lk = (lane >> 4) << 3;

  f32x4 acc[4][4];
#pragma unroll
  for (int m = 0; m < 4; ++m)
#pragma unroll
    for (int n = 0; n < 4; ++n) acc[m][n] = (f32x4){0.f, 0.f, 0.f, 0.f};

  for (int k0 = 0; k0 < HH; k0 += 32) {
    {
      u16x8v v0 = *reinterpret_cast<const u16x8v*>(Arow + k0 + akg);
      u16x8v v1 = *reinterpret_cast<const u16x8v*>(Arow + k0 + akg + 8);
      *reinterpret_cast<u16x8v*>(&As[ar * LDT + akg])     = v0;
      *reinterpret_cast<u16x8v*>(&As[ar * LDT + akg + 8]) = v1;
    }
    {
      unsigned short bv[4][4];
#pragma unroll
      for (int i = 0; i < 4; ++i) {
        float4 f = *reinterpret_cast<const float4*>(Wb + (size_t)(k0 + bk + i) * GG + cb + bc);
        bv[0][i] = f2bf(f.x); bv[1][i] = f2bf(f.y);
        bv[2][i] = f2bf(f.z); bv[3][i] = f2bf(f.w);
      }
#pragma unroll
      for (int j = 0; j < 4; ++j) {
        u16x4v w; w[0] = bv[j][0]; w[1] = bv[j][1]; w[2] = bv[j][2]; w[3] = bv[j][3];
        *reinterpret_cast<u16x4v*>(&Bs[(bc + j) * LDT + bk]) = w;
      }
    }
    __syncthreads();
    bf16x8 af[4], bfr[4];
#pragma unroll
    for (int m = 0; m < 4; ++m)
      af[m] = *reinterpret_cast<const bf16x8*>(&As[(wr + m * 16 + lr) * LDT + lk]);
#pragma unroll
    for (int n = 0; n < 4; ++n)
      bfr[n] = *reinterpret_cast<const bf16x8*>(&Bs[(wc + n * 16 + lr) * LDT + lk]);
#pragma unroll
    for (int m = 0; m < 4; ++m)
#pragma unroll
      for (int n = 0; n < 4; ++n)
        acc[m][n] = __builtin_amdgcn_mfma_f32_16x16x32_bf16(af[m], bfr[n], acc[m][n], 0, 0, 0);
    __syncthreads();
  }

  const int r0 = rb * BM + wr + ((lane >> 4) << 2);
#pragma unroll
  for (int m = 0; m < 4; ++m) {
    int sm[4];
#pragma unroll
    for (int v = 0; v < 4; ++v) sm[v] = perm[r0 + m * 16 + v];
#pragma unroll
    for (int n = 0; n < 4; ++n) {
      const int col = cb + wc + n * 16 + lr;
      const float bias = b2[e * GG + col];
#pragma unroll
      for (int v = 0; v < 4; ++v) {
        if (sm[v] >= 0)
          outg[(size_t)sm[v] * GG + col] = acc[m][n][v] + bias;
      }
    }
  }
}

// ---------------- immune: dot(H1[r], W2_imm[e]) + b2_imm[e] -----------------
__global__ __launch_bounds__(256) void immune_k(
    const int* __restrict__ hdr, const int* __restrict__ perm,
    const unsigned short* __restrict__ H1, const float* __restrict__ W2,
    const float* __restrict__ b2, float* __restrict__ out) {
  const int nrb = hdr[H_NRB];
  const int r = blockIdx.x * 4 + (threadIdx.x >> 6);
  if (r >= nrb * BM) return;
  const int b = perm[r];
  if (b < 0) return;
  const int e = hdr[H_BLK + (r >> 7)];
  const int lane = threadIdx.x & 63;
  const unsigned short* h = H1 + (size_t)r * HH + lane * 16;
  const float* w = W2 + (size_t)e * HH + lane * 16;
  float s = 0.f;
#pragma unroll
  for (int i = 0; i < 16; ++i) s += bf2f(h[i]) * w[i];
#pragma unroll
  for (int off = 32; off >= 1; off >>= 1) s += __shfl_xor(s, off, 64);
  if (lane == 0) out[b] = s + b2[e];
}

// ---------------- pass-through copies ---------------------------------------
__global__ void copy_vt(const float4* __restrict__ v, const float4* __restrict__ t,
                        float4* __restrict__ ov, float4* __restrict__ ot) {
  const int n4 = B_N * DV / 4;
  for (int i = blockIdx.x * blockDim.x + threadIdx.x; i < n4;
       i += gridDim.x * blockDim.x) {
    ov[i] = v[i];
    ot[i] = t[i];
  }
}

extern "C" void kernel_launch(void* const* d_in, const int* in_sizes, int n_in,
                              void* d_out, int out_size, void* d_ws, size_t ws_size,
                              hipStream_t stream) {
  (void)in_sizes; (void)n_in; (void)out_size; (void)ws_size;
  const float* vis = (const float*)d_in[0];
  const float* txt = (const float*)d_in[1];
  const float* W1i = (const float*)d_in[2];
  const float* b1i = (const float*)d_in[3];
  const float* W2i = (const float*)d_in[4];
  const float* b2i = (const float*)d_in[5];
  const float* W1g = (const float*)d_in[6];
  const float* b1g = (const float*)d_in[7];
  const float* W2g = (const float*)d_in[8];
  const float* b2g = (const float*)d_in[9];
  const int* organ = (const int*)d_in[10];

  float* out_imm  = (float*)d_out;
  float* out_gene = out_imm + B_N;
  float* out_vis  = out_gene + (size_t)B_N * GG;
  float* out_txt  = out_vis + (size_t)B_N * DV;

  int* hdr  = (int*)d_ws;
  int* perm = hdr + 128;
  unsigned short* H1 = (unsigned short*)((char*)d_ws + 32768);
  unsigned short* H2 = H1 + (size_t)PERM_N * HH;

  s_init<<<PERM_N / 256, 256, 0, stream>>>(hdr, perm);
  s_count<<<B_N / 256, 256, 0, stream>>>(organ, hdr);
  s_scan<<<1, 64, 0, stream>>>(hdr);
  s_scatter<<<B_N / 256, 256, 0, stream>>>(organ, hdr, perm);

  gemm_l1<<<dim3(MAXRB, HH / 128), 256, 0, stream>>>(vis, txt, W1i, b1i, hdr, perm, H1);
  gemm_l1<<<dim3(MAXRB, HH / 128), 256, 0, stream>>>(vis, txt, W1g, b1g, hdr, perm, H2);
  immune_k<<<PERM_N / 4, 256, 0, stream>>>(hdr, perm, H1, W2i, b2i, out_imm);
  gemm_l2<<<dim3(MAXRB, GG / 128), 256, 0, stream>>>(H2, W2g, b2g, hdr, perm, out_gene);
  copy_vt<<<2048, 256, 0, stream>>>((const float4*)vis, (const float4*)txt,
                                    (float4*)out_vis, (float4*)out_txt);
}

// Round 2
// 311.574 us; speedup vs baseline: 1.5566x; 1.5566x over previous
//
#include <hip/hip_runtime.h>

// MultiHeadModel routed MoE (E=8), round 2.
// New path (ws >= 176 MB):
//   s_init/count/scan/scatter : routing tables (as round 1)
//   w_cvt x3  : W1_imm, W1_gene, W2_gene  fp32 [e][k][n] -> bf16 [e][n][k] in ws
//   a_build   : permuted fused features -> bf16 Abuf[5120][2048]
//   gemm_l1_v1: H{1,2} = relu(Abuf @ W1t[e]) + b1, m97-style global_load_lds GEMM
//   immune_k  : dot per row
//   gemm_l2_v1: gene = H2 @ W2gt[e] + b2, scatter rows via perm
//   copy_vt   : pass-through
// Fallback path (small ws): round-1 kernels verbatim.

#define B_N 4096
#define DV  1024
#define DT  1024
#define DD  2048
#define HH  1024
#define GG  4096
#define EE  8
#define BM  128
#define MAXRB 40
#define PERM_N (MAXRB * BM)
#define LDT 40

typedef __bf16 bf16x8 __attribute__((ext_vector_type(8)));
typedef float f32x4 __attribute__((ext_vector_type(4)));
typedef unsigned short u16x4v __attribute__((ext_vector_type(4)));
typedef unsigned short u16x8v __attribute__((ext_vector_type(8)));

#define H_CNT 0
#define H_FIL 8
#define H_OFF 16
#define H_NRB 24
#define H_BLK 32

static __device__ __forceinline__ unsigned short f2bf(float f) {
  unsigned u = __builtin_bit_cast(unsigned, f);
  u += 0x7fffu + ((u >> 16) & 1u);
  return (unsigned short)(u >> 16);
}
static __device__ __forceinline__ float bf2f(unsigned short s) {
  return __builtin_bit_cast(float, (unsigned)s << 16);
}

// async 16B global->LDS (dst must be wave-uniform base; HW adds lane*16)
static __device__ __forceinline__ void gload16(const void* g, void* l) {
  __builtin_amdgcn_global_load_lds(
      (const __attribute__((address_space(1))) unsigned int*)g,
      (__attribute__((address_space(3))) unsigned int*)l, 16, 0, 0);
}

// ---------------- routing ----------------------------------------------------
__global__ void s_init(int* hdr, int* perm) {
  int i = blockIdx.x * 256 + threadIdx.x;
  if (i < 128) hdr[i] = 0;
  if (i < PERM_N) perm[i] = -1;
}
__global__ void s_count(const int* organ, int* hdr) {
  int b = blockIdx.x * 256 + threadIdx.x;
  if (b < B_N) atomicAdd(&hdr[H_CNT + organ[b]], 1);
}
__global__ void s_scan(int* hdr) {
  if (blockIdx.x == 0 && threadIdx.x == 0) {
    int acc = 0;
    for (int e = 0; e < EE; ++e) {
      hdr[H_OFF + e] = acc;
      int nb = (hdr[H_CNT + e] + BM - 1) >> 7;
      int rb0 = acc >> 7;
      for (int i = 0; i < nb; ++i) hdr[H_BLK + rb0 + i] = e;
      acc += nb << 7;
    }
    hdr[H_NRB] = acc >> 7;
  }
}
__global__ void s_scatter(const int* organ, int* hdr, int* perm) {
  int b = blockIdx.x * 256 + threadIdx.x;
  if (b < B_N) {
    int e = organ[b];
    int slot = hdr[H_OFF + e] + atomicAdd(&hdr[H_FIL + e], 1);
    perm[slot] = b;
  }
}

// ---------------- weight convert+transpose: fp32 [e][K][N] -> bf16 [e][N][K] -
__global__ __launch_bounds__(256) void w_cvt(const float* __restrict__ in,
                                             unsigned short* __restrict__ out,
                                             int K, int N) {
  __shared__ unsigned short ls[64][72];  // 72: keeps 16B row alignment
  const int tid = threadIdx.x;
  const int K0 = blockIdx.y << 6, N0 = blockIdx.x << 6;
  const size_t ein = (size_t)blockIdx.z * K * N;
  const int kr = tid >> 4, n0 = (tid & 15) << 2;
#pragma unroll
  for (int p = 0; p < 4; ++p) {
    int k = (p << 4) + kr;
    float4 f = *(const float4*)&in[ein + (size_t)(K0 + k) * N + N0 + n0];
    ls[n0 + 0][k] = f2bf(f.x);
    ls[n0 + 1][k] = f2bf(f.y);
    ls[n0 + 2][k] = f2bf(f.z);
    ls[n0 + 3][k] = f2bf(f.w);
  }
  __syncthreads();
  const int n = tid >> 2, kc = (tid & 3) << 4;
  u16x8v a = *(const u16x8v*)&ls[n][kc];
  u16x8v b = *(const u16x8v*)&ls[n][kc + 8];
  size_t o = (size_t)blockIdx.z * N * K + (size_t)(N0 + n) * K + K0 + kc;
  *(u16x8v*)&out[o] = a;
  *(u16x8v*)&out[o + 8] = b;
}

// ---------------- permuted fused A (bf16) ------------------------------------
__global__ void a_build(const float* __restrict__ vis, const float* __restrict__ txt,
                        const int* __restrict__ hdr, const int* __restrict__ perm,
                        unsigned short* __restrict__ Abuf) {
  const int r = blockIdx.x;
  if (r >= hdr[H_NRB] * BM) return;
  const int smp = perm[r];
  const int c = threadIdx.x << 3;
  u16x8v v;
  if (smp >= 0) {
    const float* src = (c < DV) ? vis + (size_t)smp * DV + c
                                : txt + (size_t)smp * DT + (c - DV);
    float4 a = *(const float4*)src, b = *(const float4*)(src + 4);
    v[0] = f2bf(a.x); v[1] = f2bf(a.y); v[2] = f2bf(a.z); v[3] = f2bf(a.w);
    v[4] = f2bf(b.x); v[5] = f2bf(b.y); v[6] = f2bf(b.z); v[7] = f2bf(b.w);
  } else {
#pragma unroll
    for (int i = 0; i < 8; ++i) v[i] = 0;
  }
  *(u16x8v*)&Abuf[(size_t)r * DD + c] = v;
}

// ---------------- m97-style layer-1 GEMM (both heads fused in grid.y) --------
__global__ __launch_bounds__(256) void gemm_l1_v1(
    const unsigned short* __restrict__ Abuf,
    const unsigned short* __restrict__ W1i_t, const unsigned short* __restrict__ W1g_t,
    const float* __restrict__ b1i, const float* __restrict__ b1g,
    const int* __restrict__ hdr,
    unsigned short* __restrict__ H1, unsigned short* __restrict__ H2) {
  const int rb = blockIdx.x;
  if (rb >= hdr[H_NRB]) return;
  const int head = blockIdx.y >> 3;
  const int cb = (blockIdx.y & 7) << 7;
  const int e = hdr[H_BLK + rb];
  const unsigned short* Wt = (head ? W1g_t : W1i_t) + (size_t)e * HH * DD;
  const float* bias = (head ? b1g : b1i) + e * HH;
  unsigned short* Hout = head ? H2 : H1;

  __shared__ __align__(16) unsigned short smem[16384];  // A:0..4095 B:4096..8191, epi all
  const int tid = threadIdx.x;
  const int lane = tid & 63, wave = tid >> 6;
  const int wr = (wave >> 1) << 6, wc = (wave & 1) << 6;
  const int lr = lane & 15, lk = (lane >> 4) << 3;
  const unsigned short* Arow0 = Abuf + (size_t)rb * BM * DD;

  f32x4 acc[4][4];
#pragma unroll
  for (int m = 0; m < 4; ++m)
#pragma unroll
    for (int n = 0; n < 4; ++n) acc[m][n] = (f32x4){0.f, 0.f, 0.f, 0.f};

  for (int k0 = 0; k0 < DD; k0 += 32) {
#pragma unroll
    for (int j = 0; j < 2; ++j) {
      int s = j * 256 + tid;
      int row = s >> 2, kq = (s & 3) << 3;
      gload16(Arow0 + (size_t)row * DD + k0 + kq,
              smem + ((j * 256 + (tid & 192)) << 3));
    }
#pragma unroll
    for (int j = 0; j < 2; ++j) {
      int s = j * 256 + tid;
      int row = s >> 2, kq = (s & 3) << 3;
      gload16(Wt + (size_t)(cb + row) * DD + k0 + kq,
              smem + 4096 + ((j * 256 + (tid & 192)) << 3));
    }
    __syncthreads();
    bf16x8 af[4], bfr[4];
#pragma unroll
    for (int m = 0; m < 4; ++m)
      af[m] = *(const bf16x8*)&smem[(wr + m * 16 + lr) * 32 + lk];
#pragma unroll
    for (int n = 0; n < 4; ++n)
      bfr[n] = *(const bf16x8*)&smem[4096 + (wc + n * 16 + lr) * 32 + lk];
#pragma unroll
    for (int m = 0; m < 4; ++m)
#pragma unroll
      for (int n = 0; n < 4; ++n)
        acc[m][n] = __builtin_amdgcn_mfma_f32_16x16x32_bf16(af[m], bfr[n], acc[m][n], 0, 0, 0);
    __syncthreads();
  }

  // epilogue: bias+relu -> bf16 staged in swizzled LDS -> coalesced store
  const int r0l = wr + ((lane >> 4) << 2);
#pragma unroll
  for (int n = 0; n < 4; ++n) {
    const int col = wc + n * 16 + lr;
    const float bv = bias[cb + col];
#pragma unroll
    for (int m = 0; m < 4; ++m)
#pragma unroll
      for (int v = 0; v < 4; ++v) {
        int row = r0l + m * 16 + v;
        float x = acc[m][n][v] + bv;
        x = x > 0.f ? x : 0.f;
        smem[((row << 7) + col) ^ ((row & 7) << 3)] = f2bf(x);
      }
  }
  __syncthreads();
#pragma unroll
  for (int c = 0; c < 8; ++c) {
    int q = c * 256 + tid;
    int row = q >> 4, ch = q & 15;
    int off = ((row << 7) + (ch << 3)) ^ ((row & 7) << 3);
    u16x8v val = *(const u16x8v*)&smem[off];
    *(u16x8v*)&Hout[(size_t)(rb * BM + row) * HH + cb + (ch << 3)] = val;
  }
}

// ---------------- m97-style layer-2 gene GEMM --------------------------------
__global__ __launch_bounds__(256) void gemm_l2_v1(
    const unsigned short* __restrict__ H2, const unsigned short* __restrict__ W2gt,
    const float* __restrict__ b2g, const int* __restrict__ hdr,
    const int* __restrict__ perm, float* __restrict__ outg) {
  const int rb = blockIdx.x;
  if (rb >= hdr[H_NRB]) return;
  const int cb = blockIdx.y << 7;
  const int e = hdr[H_BLK + rb];
  const unsigned short* Wt = W2gt + (size_t)e * GG * HH;

  __shared__ __align__(16) unsigned short smem[16384];
  const int tid = threadIdx.x;
  const int lane = tid & 63, wave = tid >> 6;
  const int wr = (wave >> 1) << 6, wc = (wave & 1) << 6;
  const int lr = lane & 15, lk = (lane >> 4) << 3;
  const unsigned short* Arow0 = H2 + (size_t)rb * BM * HH;

  f32x4 acc[4][4];
#pragma unroll
  for (int m = 0; m < 4; ++m)
#pragma unroll
    for (int n = 0; n < 4; ++n) acc[m][n] = (f32x4){0.f, 0.f, 0.f, 0.f};

  for (int k0 = 0; k0 < HH; k0 += 32) {
#pragma unroll
    for (int j = 0; j < 2; ++j) {
      int s = j * 256 + tid;
      int row = s >> 2, kq = (s & 3) << 3;
      gload16(Arow0 + (size_t)row * HH + k0 + kq,
              smem + ((j * 256 + (tid & 192)) << 3));
    }
#pragma unroll
    for (int j = 0; j < 2; ++j) {
      int s = j * 256 + tid;
      int row = s >> 2, kq = (s & 3) << 3;
      gload16(Wt + (size_t)(cb + row) * HH + k0 + kq,
              smem + 4096 + ((j * 256 + (tid & 192)) << 3));
    }
    __syncthreads();
    bf16x8 af[4], bfr[4];
#pragma unroll
    for (int m = 0; m < 4; ++m)
      af[m] = *(const bf16x8*)&smem[(wr + m * 16 + lr) * 32 + lk];
#pragma unroll
    for (int n = 0; n < 4; ++n)
      bfr[n] = *(const bf16x8*)&smem[4096 + (wc + n * 16 + lr) * 32 + lk];
#pragma unroll
    for (int m = 0; m < 4; ++m)
#pragma unroll
      for (int n = 0; n < 4; ++n)
        acc[m][n] = __builtin_amdgcn_mfma_f32_16x16x32_bf16(af[m], bfr[n], acc[m][n], 0, 0, 0);
    __syncthreads();
  }

  // epilogue: bias -> bf16 swizzled LDS -> fp32 scatter rows via perm
  const int r0l = wr + ((lane >> 4) << 2);
#pragma unroll
  for (int n = 0; n < 4; ++n) {
    const int col = wc + n * 16 + lr;
    const float bv = b2g[e * GG + cb + col];
#pragma unroll
    for (int m = 0; m < 4; ++m)
#pragma unroll
      for (int v = 0; v < 4; ++v) {
        int row = r0l + m * 16 + v;
        smem[((row << 7) + col) ^ ((row & 7) << 3)] = f2bf(acc[m][n][v] + bv);
      }
  }
  __syncthreads();
#pragma unroll
  for (int c = 0; c < 8; ++c) {
    int q = c * 256 + tid;
    int row = q >> 4, ch = q & 15;
    int sm = perm[rb * BM + row];
    if (sm < 0) continue;
    int off = ((row << 7) + (ch << 3)) ^ ((row & 7) << 3);
    u16x8v val = *(const u16x8v*)&smem[off];
    float4 f0, f1;
    f0.x = bf2f(val[0]); f0.y = bf2f(val[1]); f0.z = bf2f(val[2]); f0.w = bf2f(val[3]);
    f1.x = bf2f(val[4]); f1.y = bf2f(val[5]); f1.z = bf2f(val[6]); f1.w = bf2f(val[7]);
    float* dst = outg + (size_t)sm * GG + cb + (ch << 3);
    *(float4*)dst = f0;
    *(float4*)(dst + 4) = f1;
  }
}

// ---------------- immune dot -------------------------------------------------
__global__ __launch_bounds__(256) void immune_k(
    const int* __restrict__ hdr, const int* __restrict__ perm,
    const unsigned short* __restrict__ H1, const float* __restrict__ W2,
    const float* __restrict__ b2, float* __restrict__ out) {
  const int nrb = hdr[H_NRB];
  const int r = blockIdx.x * 4 + (threadIdx.x >> 6);
  if (r >= nrb * BM) return;
  const int b = perm[r];
  if (b < 0) return;
  const int e = hdr[H_BLK + (r >> 7)];
  const int lane = threadIdx.x & 63;
  const unsigned short* h = H1 + (size_t)r * HH + lane * 16;
  const float* w = W2 + (size_t)e * HH + lane * 16;
  float s = 0.f;
#pragma unroll
  for (int i = 0; i < 16; ++i) s += bf2f(h[i]) * w[i];
#pragma unroll
  for (int off = 32; off >= 1; off >>= 1) s += __shfl_xor(s, off, 64);
  if (lane == 0) out[b] = s + b2[e];
}

// ---------------- pass-through -----------------------------------------------
__global__ void copy_vt(const float4* __restrict__ v, const float4* __restrict__ t,
                        float4* __restrict__ ov, float4* __restrict__ ot) {
  const int n4 = B_N * DV / 4;
  for (int i = blockIdx.x * blockDim.x + threadIdx.x; i < n4;
       i += gridDim.x * blockDim.x) {
    ov[i] = v[i];
    ot[i] = t[i];
  }
}

// ================= round-1 fallback kernels (small ws) =======================
__global__ __launch_bounds__(256) void gemm_l1_v0(
    const float* __restrict__ vis, const float* __restrict__ txt,
    const float* __restrict__ W1, const float* __restrict__ b1,
    const int* __restrict__ hdr, const int* __restrict__ perm,
    unsigned short* __restrict__ Hout) {
  const int nrb = hdr[H_NRB];
  const int rb = blockIdx.x;
  if (rb >= nrb) return;
  const int cb = blockIdx.y << 7;
  const int e = hdr[H_BLK + rb];
  const int tid = threadIdx.x;
  __shared__ unsigned short As[BM * LDT];
  __shared__ unsigned short Bs[BM * LDT];
  const int ar = tid & 127, akg = (tid >> 7) << 4;
  const int smp = perm[rb * BM + ar];
  const int bc = (tid & 31) << 2, bk = (tid >> 5) << 2;
  const float* Wb = W1 + (size_t)e * DD * HH;
  const int wave = tid >> 6, lane = tid & 63;
  const int wr = (wave >> 1) << 6, wc = (wave & 1) << 6;
  const int lr = lane & 15, lk = (lane >> 4) << 3;
  f32x4 acc[4][4];
#pragma unroll
  for (int m = 0; m < 4; ++m)
#pragma unroll
    for (int n = 0; n < 4; ++n) acc[m][n] = (f32x4){0.f, 0.f, 0.f, 0.f};
  for (int k0 = 0; k0 < DD; k0 += 32) {
    {
      const int kk = k0 + akg;
      u16x8v v0, v1;
      if (smp >= 0) {
        const float* src = (kk < DV) ? (vis + (size_t)smp * DV + kk)
                                     : (txt + (size_t)smp * DT + (kk - DV));
#pragma unroll
        for (int i = 0; i < 2; ++i) {
          float4 f = reinterpret_cast<const float4*>(src)[i];
          v0[4 * i + 0] = f2bf(f.x); v0[4 * i + 1] = f2bf(f.y);
          v0[4 * i + 2] = f2bf(f.z); v0[4 * i + 3] = f2bf(f.w);
        }
#pragma unroll
        for (int i = 0; i < 2; ++i) {
          float4 f = reinterpret_cast<const float4*>(src)[2 + i];
          v1[4 * i + 0] = f2bf(f.x); v1[4 * i + 1] = f2bf(f.y);
          v1[4 * i + 2] = f2bf(f.z); v1[4 * i + 3] = f2bf(f.w);
        }
      } else {
#pragma unroll
        for (int i = 0; i < 8; ++i) { v0[i] = 0; v1[i] = 0; }
      }
      *reinterpret_cast<u16x8v*>(&As[ar * LDT + akg]) = v0;
      *reinterpret_cast<u16x8v*>(&As[ar * LDT + akg + 8]) = v1;
    }
    {
      unsigned short bv[4][4];
#pragma unroll
      for (int i = 0; i < 4; ++i) {
        float4 f = *reinterpret_cast<const float4*>(Wb + (size_t)(k0 + bk + i) * HH + cb + bc);
        bv[0][i] = f2bf(f.x); bv[1][i] = f2bf(f.y);
        bv[2][i] = f2bf(f.z); bv[3][i] = f2bf(f.w);
      }
#pragma unroll
      for (int j = 0; j < 4; ++j) {
        u16x4v w; w[0] = bv[j][0]; w[1] = bv[j][1]; w[2] = bv[j][2]; w[3] = bv[j][3];
        *reinterpret_cast<u16x4v*>(&Bs[(bc + j) * LDT + bk]) = w;
      }
    }
    __syncthreads();
    bf16x8 af[4], bfr[4];
#pragma unroll
    for (int m = 0; m < 4; ++m)
      af[m] = *reinterpret_cast<const bf16x8*>(&As[(wr + m * 16 + lr) * LDT + lk]);
#pragma unroll
    for (int n = 0; n < 4; ++n)
      bfr[n] = *reinterpret_cast<const bf16x8*>(&Bs[(wc + n * 16 + lr) * LDT + lk]);
#pragma unroll
    for (int m = 0; m < 4; ++m)
#pragma unroll
      for (int n = 0; n < 4; ++n)
        acc[m][n] = __builtin_amdgcn_mfma_f32_16x16x32_bf16(af[m], bfr[n], acc[m][n], 0, 0, 0);
    __syncthreads();
  }
  const int r0 = rb * BM + wr + ((lane >> 4) << 2);
#pragma unroll
  for (int n = 0; n < 4; ++n) {
    const int col = cb + wc + n * 16 + lr;
    const float bias = b1[e * HH + col];
#pragma unroll
    for (int m = 0; m < 4; ++m)
#pragma unroll
      for (int v = 0; v < 4; ++v) {
        float x = acc[m][n][v] + bias;
        x = x > 0.f ? x : 0.f;
        Hout[(size_t)(r0 + m * 16 + v) * HH + col] = f2bf(x);
      }
  }
}

__global__ __launch_bounds__(256) void gemm_l2_v0(
    const unsigned short* __restrict__ H2, const float* __restrict__ W2,
    const float* __restrict__ b2, const int* __restrict__ hdr,
    const int* __restrict__ perm, float* __restrict__ outg) {
  const int nrb = hdr[H_NRB];
  const int rb = blockIdx.x;
  if (rb >= nrb) return;
  const int cb = blockIdx.y << 7;
  const int e = hdr[H_BLK + rb];
  const int tid = threadIdx.x;
  __shared__ unsigned short As[BM * LDT];
  __shared__ unsigned short Bs[BM * LDT];
  const int ar = tid & 127, akg = (tid >> 7) << 4;
  const unsigned short* Arow = H2 + (size_t)(rb * BM + ar) * HH;
  const int bc = (tid & 31) << 2, bk = (tid >> 5) << 2;
  const float* Wb = W2 + (size_t)e * HH * GG;
  const int wave = tid >> 6, lane = tid & 63;
  const int wr = (wave >> 1) << 6, wc = (wave & 1) << 6;
  const int lr = lane & 15, lk = (lane >> 4) << 3;
  f32x4 acc[4][4];
#pragma unroll
  for (int m = 0; m < 4; ++m)
#pragma unroll
    for (int n = 0; n < 4; ++n) acc[m][n] = (f32x4){0.f, 0.f, 0.f, 0.f};
  for (int k0 = 0; k0 < HH; k0 += 32) {
    {
      u16x8v v0 = *reinterpret_cast<const u16x8v*>(Arow + k0 + akg);
      u16x8v v1 = *reinterpret_cast<const u16x8v*>(Arow + k0 + akg + 8);
      *reinterpret_cast<u16x8v*>(&As[ar * LDT + akg]) = v0;
      *reinterpret_cast<u16x8v*>(&As[ar * LDT + akg + 8]) = v1;
    }
    {
      unsigned short bv[4][4];
#pragma unroll
      for (int i = 0; i < 4; ++i) {
        float4 f = *reinterpret_cast<const float4*>(Wb + (size_t)(k0 + bk + i) * GG + cb + bc);
        bv[0][i] = f2bf(f.x); bv[1][i] = f2bf(f.y);
        bv[2][i] = f2bf(f.z); bv[3][i] = f2bf(f.w);
      }
#pragma unroll
      for (int j = 0; j < 4; ++j) {
        u16x4v w; w[0] = bv[j][0]; w[1] = bv[j][1]; w[2] = bv[j][2]; w[3] = bv[j][3];
        *reinterpret_cast<u16x4v*>(&Bs[(bc + j) * LDT + bk]) = w;
      }
    }
    __syncthreads();
    bf16x8 af[4], bfr[4];
#pragma unroll
    for (int m = 0; m < 4; ++m)
      af[m] = *reinterpret_cast<const bf16x8*>(&As[(wr + m * 16 + lr) * LDT + lk]);
#pragma unroll
    for (int n = 0; n < 4; ++n)
      bfr[n] = *reinterpret_cast<const bf16x8*>(&Bs[(wc + n * 16 + lr) * LDT + lk]);
#pragma unroll
    for (int m = 0; m < 4; ++m)
#pragma unroll
      for (int n = 0; n < 4; ++n)
        acc[m][n] = __builtin_amdgcn_mfma_f32_16x16x32_bf16(af[m], bfr[n], acc[m][n], 0, 0, 0);
    __syncthreads();
  }
  const int r0 = rb * BM + wr + ((lane >> 4) << 2);
#pragma unroll
  for (int m = 0; m < 4; ++m) {
    int sm[4];
#pragma unroll
    for (int v = 0; v < 4; ++v) sm[v] = perm[r0 + m * 16 + v];
#pragma unroll
    for (int n = 0; n < 4; ++n) {
      const int col = cb + wc + n * 16 + lr;
      const float bias = b2[e * GG + col];
#pragma unroll
      for (int v = 0; v < 4; ++v)
        if (sm[v] >= 0) outg[(size_t)sm[v] * GG + col] = acc[m][n][v] + bias;
    }
  }
}

// ================= host ======================================================
extern "C" void kernel_launch(void* const* d_in, const int* in_sizes, int n_in,
                              void* d_out, int out_size, void* d_ws, size_t ws_size,
                              hipStream_t stream) {
  (void)in_sizes; (void)n_in; (void)out_size;
  const float* vis = (const float*)d_in[0];
  const float* txt = (const float*)d_in[1];
  const float* W1i = (const float*)d_in[2];
  const float* b1i = (const float*)d_in[3];
  const float* W2i = (const float*)d_in[4];
  const float* b2i = (const float*)d_in[5];
  const float* W1g = (const float*)d_in[6];
  const float* b1g = (const float*)d_in[7];
  const float* W2g = (const float*)d_in[8];
  const float* b2g = (const float*)d_in[9];
  const int* organ = (const int*)d_in[10];

  float* out_imm = (float*)d_out;
  float* out_gene = out_imm + B_N;
  float* out_vis = out_gene + (size_t)B_N * GG;
  float* out_txt = out_vis + (size_t)B_N * DV;

  int* hdr = (int*)d_ws;
  int* perm = hdr + 128;

  // ws layout (new path):
  const size_t OFF_ABUF = 32768;
  const size_t OFF_H1 = OFF_ABUF + (size_t)PERM_N * DD * 2;          // 21004288
  const size_t OFF_H2 = OFF_H1 + (size_t)PERM_N * HH * 2;            // 31490048
  const size_t OFF_W1I = OFF_H2 + (size_t)PERM_N * HH * 2;           // 41975808
  const size_t OFF_W1G = OFF_W1I + (size_t)EE * HH * DD * 2;         // 75530240
  const size_t OFF_W2G = OFF_W1G + (size_t)EE * HH * DD * 2;         // 109084672
  const size_t NEED = OFF_W2G + (size_t)EE * GG * HH * 2;            // 176193536

  s_init<<<PERM_N / 256, 256, 0, stream>>>(hdr, perm);
  s_count<<<B_N / 256, 256, 0, stream>>>(organ, hdr);
  s_scan<<<1, 64, 0, stream>>>(hdr);
  s_scatter<<<B_N / 256, 256, 0, stream>>>(organ, hdr, perm);

  if (ws_size >= NEED) {
    unsigned short* Abuf = (unsigned short*)((char*)d_ws + OFF_ABUF);
    unsigned short* H1 = (unsigned short*)((char*)d_ws + OFF_H1);
    unsigned short* H2 = (unsigned short*)((char*)d_ws + OFF_H2);
    unsigned short* W1i_t = (unsigned short*)((char*)d_ws + OFF_W1I);
    unsigned short* W1g_t = (unsigned short*)((char*)d_ws + OFF_W1G);
    unsigned short* W2g_t = (unsigned short*)((char*)d_ws + OFF_W2G);

    w_cvt<<<dim3(HH / 64, DD / 64, EE), 256, 0, stream>>>(W1i, W1i_t, DD, HH);
    w_cvt<<<dim3(HH / 64, DD / 64, EE), 256, 0, stream>>>(W1g, W1g_t, DD, HH);
    w_cvt<<<dim3(GG / 64, HH / 64, EE), 256, 0, stream>>>(W2g, W2g_t, HH, GG);
    a_build<<<PERM_N, 256, 0, stream>>>(vis, txt, hdr, perm, Abuf);

    gemm_l1_v1<<<dim3(MAXRB, 16), 256, 0, stream>>>(Abuf, W1i_t, W1g_t, b1i, b1g,
                                                    hdr, H1, H2);
    immune_k<<<PERM_N / 4, 256, 0, stream>>>(hdr, perm, H1, W2i, b2i, out_imm);
    gemm_l2_v1<<<dim3(MAXRB, GG / 128), 256, 0, stream>>>(H2, W2g_t, b2g, hdr,
                                                          perm, out_gene);
  } else {
    unsigned short* H1 = (unsigned short*)((char*)d_ws + 32768);
    unsigned short* H2 = H1 + (size_t)PERM_N * HH;
    gemm_l1_v0<<<dim3(MAXRB, HH / 128), 256, 0, stream>>>(vis, txt, W1i, b1i, hdr, perm, H1);
    gemm_l1_v0<<<dim3(MAXRB, HH / 128), 256, 0, stream>>>(vis, txt, W1g, b1g, hdr, perm, H2);
    immune_k<<<PERM_N / 4, 256, 0, stream>>>(hdr, perm, H1, W2i, b2i, out_imm);
    gemm_l2_v0<<<dim3(MAXRB, GG / 128), 256, 0, stream>>>(H2, W2g, b2g, hdr, perm, out_gene);
  }
  copy_vt<<<2048, 256, 0, stream>>>((const float4*)vis, (const float4*)txt,
                                    (float4*)out_vis, (float4*)out_txt);
}

// Round 3
// 253.700 us; speedup vs baseline: 1.9117x; 1.2281x over previous
//
#include <hip/hip_runtime.h>

// MultiHeadModel routed MoE (E=8), round 3.
//   routing  : single-block (init+count+scan+scatter)
//   k_prep   : w_cvt(W1_imm) ∥ w_cvt(W1_gene) ∥ a_build      (all BW-bound, indep)
//   k_main1  : gemm_l1 (both heads) ∥ w_cvt(W2_gene) ∥ copy_vt
//   k_main2  : gemm_l2 ∥ immune
// GEMMs: 128x128 tile, 2-phase double-buffered LDS (global_load_lds 16B),
// ONE barrier per K-step (load latency hides under ds_read+MFMA).

#define B_N 4096
#define DV  1024
#define DT  1024
#define DD  2048
#define HH  1024
#define GG  4096
#define EE  8
#define BM  128
#define MAXRB 40
#define PERM_N (MAXRB * BM)
#define LDT 40

typedef __bf16 bf16x8 __attribute__((ext_vector_type(8)));
typedef float f32x4 __attribute__((ext_vector_type(4)));
typedef unsigned short u16x4v __attribute__((ext_vector_type(4)));
typedef unsigned short u16x8v __attribute__((ext_vector_type(8)));

#define H_CNT 0
#define H_FIL 8
#define H_OFF 16
#define H_NRB 24
#define H_BLK 32

static __device__ __forceinline__ unsigned short f2bf(float f) {
  unsigned u = __builtin_bit_cast(unsigned, f);
  u += 0x7fffu + ((u >> 16) & 1u);
  return (unsigned short)(u >> 16);
}
static __device__ __forceinline__ float bf2f(unsigned short s) {
  return __builtin_bit_cast(float, (unsigned)s << 16);
}
static __device__ __forceinline__ void gload16(const void* g, void* l) {
  __builtin_amdgcn_global_load_lds(
      (const __attribute__((address_space(1))) unsigned int*)g,
      (__attribute__((address_space(3))) unsigned int*)l, 16, 0, 0);
}

// ---------------- routing: one block, 1024 threads ---------------------------
__global__ __launch_bounds__(1024) void routing(const int* __restrict__ organ,
                                                int* __restrict__ hdr,
                                                int* __restrict__ perm) {
  __shared__ int cnt[EE], fil[EE], off[EE];
  const int tid = threadIdx.x;
  if (tid < EE) { cnt[tid] = 0; fil[tid] = 0; }
  __syncthreads();
#pragma unroll
  for (int i = 0; i < 4; ++i) atomicAdd(&cnt[organ[tid + (i << 10)]], 1);
#pragma unroll
  for (int i = 0; i < 5; ++i) perm[tid + (i << 10)] = -1;
  __syncthreads();
  if (tid == 0) {
    int acc = 0;
    for (int e = 0; e < EE; ++e) {
      off[e] = acc;
      hdr[H_OFF + e] = acc;
      hdr[H_CNT + e] = cnt[e];
      int nb = (cnt[e] + BM - 1) >> 7;
      int rb0 = acc >> 7;
      for (int i = 0; i < nb; ++i) hdr[H_BLK + rb0 + i] = e;
      acc += nb << 7;
    }
    hdr[H_NRB] = acc >> 7;
  }
  __syncthreads();
#pragma unroll
  for (int i = 0; i < 4; ++i) {
    int b = tid + (i << 10);
    int e = organ[b];
    int slot = off[e] + atomicAdd(&fil[e], 1);
    perm[slot] = b;
  }
}

// ---------------- weight convert+transpose body ------------------------------
static __device__ __forceinline__ void wcvt_body(
    const float* __restrict__ in, unsigned short* __restrict__ out,
    int K, int N, int bx, unsigned short* ls) {  // ls: 64*72 shorts
  const int nn = N >> 6, nk = K >> 6;
  const int e = bx / (nk * nn);
  int rem = bx - e * nk * nn;
  const int K0 = (rem / nn) << 6, N0 = (rem % nn) << 6;
  const size_t ein = (size_t)e * K * N;
  const int tid = threadIdx.x;
  const int kr = tid >> 4, n0 = (tid & 15) << 2;
#pragma unroll
  for (int p = 0; p < 4; ++p) {
    int k = (p << 4) + kr;
    float4 f = *(const float4*)&in[ein + (size_t)(K0 + k) * N + N0 + n0];
    ls[(n0 + 0) * 72 + k] = f2bf(f.x);
    ls[(n0 + 1) * 72 + k] = f2bf(f.y);
    ls[(n0 + 2) * 72 + k] = f2bf(f.z);
    ls[(n0 + 3) * 72 + k] = f2bf(f.w);
  }
  __syncthreads();
  const int n = tid >> 2, kc = (tid & 3) << 4;
  u16x8v a = *(const u16x8v*)&ls[n * 72 + kc];
  u16x8v b = *(const u16x8v*)&ls[n * 72 + kc + 8];
  size_t o = (size_t)e * N * K + (size_t)(N0 + n) * K + K0 + kc;
  *(u16x8v*)&out[o] = a;
  *(u16x8v*)&out[o + 8] = b;
}

// ---------------- a_build body: 4 rows per block -----------------------------
static __device__ __forceinline__ void abuild_body(
    int bx, const float* __restrict__ vis, const float* __restrict__ txt,
    const int* __restrict__ hdr, const int* __restrict__ perm,
    unsigned short* __restrict__ Abuf) {
  const int nr = hdr[H_NRB] << 7;
  const int tid = threadIdx.x;
  const int c = tid << 3;
  const float* srcbase = (c < DV) ? vis : txt;
  const int cc = (c < DV) ? c : c - DV;
#pragma unroll
  for (int p = 0; p < 4; ++p) {
    int r = (bx << 2) + p;
    if (r >= nr) return;
    int smp = perm[r];
    u16x8v v;
    if (smp >= 0) {
      const float* src = srcbase + (size_t)smp * 1024 + cc;
      float4 a = *(const float4*)src, b = *(const float4*)(src + 4);
      v[0] = f2bf(a.x); v[1] = f2bf(a.y); v[2] = f2bf(a.z); v[3] = f2bf(a.w);
      v[4] = f2bf(b.x); v[5] = f2bf(b.y); v[6] = f2bf(b.z); v[7] = f2bf(b.w);
    } else {
#pragma unroll
      for (int i = 0; i < 8; ++i) v[i] = 0;
    }
    *(u16x8v*)&Abuf[(size_t)r * DD + c] = v;
  }
}

// ---------------- 2-phase double-buffered GEMM main loop ---------------------
// smem layout (shorts): A0 @0, A1 @4096, B0 @8192, B1 @12288  (32 KiB total)
template <int KDIM>
static __device__ __forceinline__ void gemm_main(
    const unsigned short* __restrict__ Aseg,   // 128 x KDIM, row-major
    const unsigned short* __restrict__ Bseg,   // 128 x KDIM, row-major
    unsigned short* smem, f32x4 (&acc)[4][4]) {
  const int tid = threadIdx.x;
  const int lane = tid & 63, wave = tid >> 6;
  const int wr = (wave >> 1) << 6, wc = (wave & 1) << 6;
  const int lr = lane & 15, lk = (lane >> 4) << 3;
  const int j0row = tid >> 2;              // 0..63
  const int kq = (tid & 3) << 3;
  const int wbase = (tid & 192) << 3;      // wave's 1KB slot (shorts)
  constexpr int NT = KDIM / 32;

  auto stage = [&](int buf, int k0) {
#pragma unroll
    for (int j = 0; j < 2; ++j) {
      const int row = (j << 6) + j0row;
      gload16(Aseg + (size_t)row * KDIM + k0 + kq,
              smem + (buf << 12) + (j << 11) + wbase);
      gload16(Bseg + (size_t)row * KDIM + k0 + kq,
              smem + 8192 + (buf << 12) + (j << 11) + wbase);
    }
  };

  stage(0, 0);
  asm volatile("s_waitcnt vmcnt(0)" ::: "memory");
  __syncthreads();
#pragma unroll 2
  for (int kt = 0; kt < NT; ++kt) {
    const int cur = kt & 1;
    if (kt + 1 < NT) stage(cur ^ 1, (kt + 1) << 5);
    bf16x8 af[4], bfr[4];
#pragma unroll
    for (int m = 0; m < 4; ++m)
      af[m] = *(const bf16x8*)&smem[(cur << 12) + (wr + m * 16 + lr) * 32 + lk];
#pragma unroll
    for (int n = 0; n < 4; ++n)
      bfr[n] = *(const bf16x8*)&smem[8192 + (cur << 12) + (wc + n * 16 + lr) * 32 + lk];
#pragma unroll
    for (int m = 0; m < 4; ++m)
#pragma unroll
      for (int n = 0; n < 4; ++n)
        acc[m][n] = __builtin_amdgcn_mfma_f32_16x16x32_bf16(af[m], bfr[n], acc[m][n], 0, 0, 0);
    asm volatile("s_waitcnt vmcnt(0)" ::: "memory");
    __syncthreads();
  }
}

// ---------------- gemm bodies ------------------------------------------------
static __device__ void gemm_l1_body(
    int bx, const unsigned short* __restrict__ Abuf,
    const unsigned short* __restrict__ W1i_t, const unsigned short* __restrict__ W1g_t,
    const float* __restrict__ b1i, const float* __restrict__ b1g,
    const int* __restrict__ hdr, unsigned short* __restrict__ H1,
    unsigned short* __restrict__ H2, unsigned short* smem) {
  const int rb = bx % MAXRB;
  const int cy = bx / MAXRB;                // 0..15
  if (rb >= hdr[H_NRB]) return;
  const int head = cy >> 3;
  const int cb = (cy & 7) << 7;
  const int e = hdr[H_BLK + rb];
  const unsigned short* Wt = (head ? W1g_t : W1i_t) + (size_t)e * HH * DD;
  const float* bias = (head ? b1g : b1i) + e * HH;
  unsigned short* Hout = head ? H2 : H1;
  const int tid = threadIdx.x;
  const int lane = tid & 63, wave = tid >> 6;
  const int wr = (wave >> 1) << 6, wc = (wave & 1) << 6;
  const int lr = lane & 15;

  f32x4 acc[4][4];
#pragma unroll
  for (int m = 0; m < 4; ++m)
#pragma unroll
    for (int n = 0; n < 4; ++n) acc[m][n] = (f32x4){0.f, 0.f, 0.f, 0.f};

  gemm_main<DD>(Abuf + (size_t)rb * BM * DD, Wt + (size_t)cb * DD, smem, acc);

  const int r0l = wr + ((lane >> 4) << 2);
#pragma unroll
  for (int n = 0; n < 4; ++n) {
    const int col = wc + n * 16 + lr;
    const float bv = bias[cb + col];
#pragma unroll
    for (int m = 0; m < 4; ++m)
#pragma unroll
      for (int v = 0; v < 4; ++v) {
        int row = r0l + m * 16 + v;
        float x = acc[m][n][v] + bv;
        x = x > 0.f ? x : 0.f;
        smem[((row << 7) + col) ^ ((row & 7) << 3)] = f2bf(x);
      }
  }
  __syncthreads();
#pragma unroll
  for (int c = 0; c < 8; ++c) {
    int q = c * 256 + tid;
    int row = q >> 4, ch = q & 15;
    int off = ((row << 7) + (ch << 3)) ^ ((row & 7) << 3);
    u16x8v val = *(const u16x8v*)&smem[off];
    *(u16x8v*)&Hout[(size_t)(rb * BM + row) * HH + cb + (ch << 3)] = val;
  }
}

static __device__ void gemm_l2_body(
    int bx, const unsigned short* __restrict__ H2buf,
    const unsigned short* __restrict__ W2gt, const float* __restrict__ b2g,
    const int* __restrict__ hdr, const int* __restrict__ perm,
    float* __restrict__ outg, unsigned short* smem) {
  const int rb = bx % MAXRB;
  const int cb = (bx / MAXRB) << 7;         // 0..31 col-blocks
  if (rb >= hdr[H_NRB]) return;
  const int e = hdr[H_BLK + rb];
  const int tid = threadIdx.x;
  const int lane = tid & 63, wave = tid >> 6;
  const int wr = (wave >> 1) << 6, wc = (wave & 1) << 6;
  const int lr = lane & 15;

  f32x4 acc[4][4];
#pragma unroll
  for (int m = 0; m < 4; ++m)
#pragma unroll
    for (int n = 0; n < 4; ++n) acc[m][n] = (f32x4){0.f, 0.f, 0.f, 0.f};

  gemm_main<HH>(H2buf + (size_t)rb * BM * HH,
                W2gt + (size_t)e * GG * HH + (size_t)cb * HH, smem, acc);

  const int r0l = wr + ((lane >> 4) << 2);
#pragma unroll
  for (int n = 0; n < 4; ++n) {
    const int col = wc + n * 16 + lr;
    const float bv = b2g[e * GG + cb + col];
#pragma unroll
    for (int m = 0; m < 4; ++m)
#pragma unroll
      for (int v = 0; v < 4; ++v) {
        int row = r0l + m * 16 + v;
        smem[((row << 7) + col) ^ ((row & 7) << 3)] = f2bf(acc[m][n][v] + bv);
      }
  }
  __syncthreads();
#pragma unroll
  for (int c = 0; c < 8; ++c) {
    int q = c * 256 + tid;
    int row = q >> 4, ch = q & 15;
    int sm = perm[rb * BM + row];
    if (sm < 0) continue;
    int off = ((row << 7) + (ch << 3)) ^ ((row & 7) << 3);
    u16x8v val = *(const u16x8v*)&smem[off];
    float4 f0, f1;
    f0.x = bf2f(val[0]); f0.y = bf2f(val[1]); f0.z = bf2f(val[2]); f0.w = bf2f(val[3]);
    f1.x = bf2f(val[4]); f1.y = bf2f(val[5]); f1.z = bf2f(val[6]); f1.w = bf2f(val[7]);
    float* dst = outg + (size_t)sm * GG + cb + (ch << 3);
    *(float4*)dst = f0;
    *(float4*)(dst + 4) = f1;
  }
}

static __device__ __forceinline__ void immune_body(
    int bx, const int* __restrict__ hdr, const int* __restrict__ perm,
    const unsigned short* __restrict__ H1, const float* __restrict__ W2,
    const float* __restrict__ b2, float* __restrict__ out) {
  const int nrb = hdr[H_NRB];
  const int r = bx * 4 + (threadIdx.x >> 6);
  if (r >= nrb * BM) return;
  const int b = perm[r];
  if (b < 0) return;
  const int e = hdr[H_BLK + (r >> 7)];
  const int lane = threadIdx.x & 63;
  const unsigned short* h = H1 + (size_t)r * HH + lane * 16;
  const float* w = W2 + (size_t)e * HH + lane * 16;
  float s = 0.f;
#pragma unroll
  for (int i = 0; i < 16; ++i) s += bf2f(h[i]) * w[i];
#pragma unroll
  for (int off = 32; off >= 1; off >>= 1) s += __shfl_xor(s, off, 64);
  if (lane == 0) out[b] = s + b2[e];
}

static __device__ __forceinline__ void copy_body(
    int bx, const float4* __restrict__ v, const float4* __restrict__ t,
    float4* __restrict__ ov, float4* __restrict__ ot) {
  const int n4 = B_N * DV / 4;
  for (int i = bx * 256 + (int)threadIdx.x; i < n4; i += 1024 * 256) {
    ov[i] = v[i];
    ot[i] = t[i];
  }
}

// ---------------- fused dispatches -------------------------------------------
#define G_CVT1 (EE * (DD >> 6) * (HH >> 6))   // 4096
#define G_AB   (PERM_N / 4)                   // 1280
#define G_L1   (MAXRB * 16)                   // 640
#define G_CVT2 (EE * (HH >> 6) * (GG >> 6))   // 8192
#define G_COPY 1024
#define G_L2   (MAXRB * 32)                   // 1280
#define G_IMM  (PERM_N / 4)                   // 1280

__global__ __launch_bounds__(256) void k_prep(
    const float* __restrict__ W1i, const float* __restrict__ W1g,
    unsigned short* __restrict__ W1i_t, unsigned short* __restrict__ W1g_t,
    const float* __restrict__ vis, const float* __restrict__ txt,
    const int* __restrict__ hdr, const int* __restrict__ perm,
    unsigned short* __restrict__ Abuf) {
  __shared__ __align__(16) unsigned short sm[64 * 72];
  int bx = blockIdx.x;
  if (bx < G_CVT1) { wcvt_body(W1i, W1i_t, DD, HH, bx, sm); return; }
  bx -= G_CVT1;
  if (bx < G_CVT1) { wcvt_body(W1g, W1g_t, DD, HH, bx, sm); return; }
  bx -= G_CVT1;
  abuild_body(bx, vis, txt, hdr, perm, Abuf);
}

__global__ __launch_bounds__(256) void k_main1(
    const unsigned short* __restrict__ Abuf,
    const unsigned short* __restrict__ W1i_t, const unsigned short* __restrict__ W1g_t,
    const float* __restrict__ b1i, const float* __restrict__ b1g,
    const int* __restrict__ hdr, unsigned short* __restrict__ H1,
    unsigned short* __restrict__ H2, const float* __restrict__ W2g,
    unsigned short* __restrict__ W2g_t, const float4* __restrict__ vis4,
    const float4* __restrict__ txt4, float4* __restrict__ ov,
    float4* __restrict__ ot) {
  __shared__ __align__(16) unsigned short smem[16384];
  int bx = blockIdx.x;
  if (bx < G_L1) {
    gemm_l1_body(bx, Abuf, W1i_t, W1g_t, b1i, b1g, hdr, H1, H2, smem);
    return;
  }
  bx -= G_L1;
  if (bx < G_CVT2) { wcvt_body(W2g, W2g_t, HH, GG, bx, smem); return; }
  bx -= G_CVT2;
  copy_body(bx, vis4, txt4, ov, ot);
}

__global__ __launch_bounds__(256) void k_main2(
    const unsigned short* __restrict__ H2buf,
    const unsigned short* __restrict__ W2gt, const float* __restrict__ b2g,
    const int* __restrict__ hdr, const int* __restrict__ perm,
    float* __restrict__ outg, const unsigned short* __restrict__ H1,
    const float* __restrict__ W2i, const float* __restrict__ b2i,
    float* __restrict__ outi) {
  __shared__ __align__(16) unsigned short smem[16384];
  int bx = blockIdx.x;
  if (bx < G_L2) {
    gemm_l2_body(bx, H2buf, W2gt, b2g, hdr, perm, outg, smem);
    return;
  }
  bx -= G_L2;
  immune_body(bx, hdr, perm, H1, W2i, b2i, outi);
}

// ================= round-1 fallback kernels (small ws) =======================
__global__ __launch_bounds__(256) void gemm_l1_v0(
    const float* __restrict__ vis, const float* __restrict__ txt,
    const float* __restrict__ W1, const float* __restrict__ b1,
    const int* __restrict__ hdr, const int* __restrict__ perm,
    unsigned short* __restrict__ Hout) {
  const int nrb = hdr[H_NRB];
  const int rb = blockIdx.x;
  if (rb >= nrb) return;
  const int cb = blockIdx.y << 7;
  const int e = hdr[H_BLK + rb];
  const int tid = threadIdx.x;
  __shared__ unsigned short As[BM * LDT];
  __shared__ unsigned short Bs[BM * LDT];
  const int ar = tid & 127, akg = (tid >> 7) << 4;
  const int smp = perm[rb * BM + ar];
  const int bc = (tid & 31) << 2, bk = (tid >> 5) << 2;
  const float* Wb = W1 + (size_t)e * DD * HH;
  const int wave = tid >> 6, lane = tid & 63;
  const int wr = (wave >> 1) << 6, wc = (wave & 1) << 6;
  const int lr = lane & 15, lk = (lane >> 4) << 3;
  f32x4 acc[4][4];
#pragma unroll
  for (int m = 0; m < 4; ++m)
#pragma unroll
    for (int n = 0; n < 4; ++n) acc[m][n] = (f32x4){0.f, 0.f, 0.f, 0.f};
  for (int k0 = 0; k0 < DD; k0 += 32) {
    {
      const int kk = k0 + akg;
      u16x8v v0, v1;
      if (smp >= 0) {
        const float* src = (kk < DV) ? (vis + (size_t)smp * DV + kk)
                                     : (txt + (size_t)smp * DT + (kk - DV));
#pragma unroll
        for (int i = 0; i < 2; ++i) {
          float4 f = reinterpret_cast<const float4*>(src)[i];
          v0[4 * i + 0] = f2bf(f.x); v0[4 * i + 1] = f2bf(f.y);
          v0[4 * i + 2] = f2bf(f.z); v0[4 * i + 3] = f2bf(f.w);
        }
#pragma unroll
        for (int i = 0; i < 2; ++i) {
          float4 f = reinterpret_cast<const float4*>(src)[2 + i];
          v1[4 * i + 0] = f2bf(f.x); v1[4 * i + 1] = f2bf(f.y);
          v1[4 * i + 2] = f2bf(f.z); v1[4 * i + 3] = f2bf(f.w);
        }
      } else {
#pragma unroll
        for (int i = 0; i < 8; ++i) { v0[i] = 0; v1[i] = 0; }
      }
      *reinterpret_cast<u16x8v*>(&As[ar * LDT + akg]) = v0;
      *reinterpret_cast<u16x8v*>(&As[ar * LDT + akg + 8]) = v1;
    }
    {
      unsigned short bv[4][4];
#pragma unroll
      for (int i = 0; i < 4; ++i) {
        float4 f = *reinterpret_cast<const float4*>(Wb + (size_t)(k0 + bk + i) * HH + cb + bc);
        bv[0][i] = f2bf(f.x); bv[1][i] = f2bf(f.y);
        bv[2][i] = f2bf(f.z); bv[3][i] = f2bf(f.w);
      }
#pragma unroll
      for (int j = 0; j < 4; ++j) {
        u16x4v w; w[0] = bv[j][0]; w[1] = bv[j][1]; w[2] = bv[j][2]; w[3] = bv[j][3];
        *reinterpret_cast<u16x4v*>(&Bs[(bc + j) * LDT + bk]) = w;
      }
    }
    __syncthreads();
    bf16x8 af[4], bfr[4];
#pragma unroll
    for (int m = 0; m < 4; ++m)
      af[m] = *reinterpret_cast<const bf16x8*>(&As[(wr + m * 16 + lr) * LDT + lk]);
#pragma unroll
    for (int n = 0; n < 4; ++n)
      bfr[n] = *reinterpret_cast<const bf16x8*>(&Bs[(wc + n * 16 + lr) * LDT + lk]);
#pragma unroll
    for (int m = 0; m < 4; ++m)
#pragma unroll
      for (int n = 0; n < 4; ++n)
        acc[m][n] = __builtin_amdgcn_mfma_f32_16x16x32_bf16(af[m], bfr[n], acc[m][n], 0, 0, 0);
    __syncthreads();
  }
  const int r0 = rb * BM + wr + ((lane >> 4) << 2);
#pragma unroll
  for (int n = 0; n < 4; ++n) {
    const int col = cb + wc + n * 16 + lr;
    const float bias = b1[e * HH + col];
#pragma unroll
    for (int m = 0; m < 4; ++m)
#pragma unroll
      for (int v = 0; v < 4; ++v) {
        float x = acc[m][n][v] + bias;
        x = x > 0.f ? x : 0.f;
        Hout[(size_t)(r0 + m * 16 + v) * HH + col] = f2bf(x);
      }
  }
}

__global__ __launch_bounds__(256) void gemm_l2_v0(
    const unsigned short* __restrict__ H2, const float* __restrict__ W2,
    const float* __restrict__ b2, const int* __restrict__ hdr,
    const int* __restrict__ perm, float* __restrict__ outg) {
  const int nrb = hdr[H_NRB];
  const int rb = blockIdx.x;
  if (rb >= nrb) return;
  const int cb = blockIdx.y << 7;
  const int e = hdr[H_BLK + rb];
  const int tid = threadIdx.x;
  __shared__ unsigned short As[BM * LDT];
  __shared__ unsigned short Bs[BM * LDT];
  const int ar = tid & 127, akg = (tid >> 7) << 4;
  const unsigned short* Arow = H2 + (size_t)(rb * BM + ar) * HH;
  const int bc = (tid & 31) << 2, bk = (tid >> 5) << 2;
  const float* Wb = W2 + (size_t)e * HH * GG;
  const int wave = tid >> 6, lane = tid & 63;
  const int wr = (wave >> 1) << 6, wc = (wave & 1) << 6;
  const int lr = lane & 15, lk = (lane >> 4) << 3;
  f32x4 acc[4][4];
#pragma unroll
  for (int m = 0; m < 4; ++m)
#pragma unroll
    for (int n = 0; n < 4; ++n) acc[m][n] = (f32x4){0.f, 0.f, 0.f, 0.f};
  for (int k0 = 0; k0 < HH; k0 += 32) {
    {
      u16x8v v0 = *reinterpret_cast<const u16x8v*>(Arow + k0 + akg);
      u16x8v v1 = *reinterpret_cast<const u16x8v*>(Arow + k0 + akg + 8);
      *reinterpret_cast<u16x8v*>(&As[ar * LDT + akg]) = v0;
      *reinterpret_cast<u16x8v*>(&As[ar * LDT + akg + 8]) = v1;
    }
    {
      unsigned short bv[4][4];
#pragma unroll
      for (int i = 0; i < 4; ++i) {
        float4 f = *reinterpret_cast<const float4*>(Wb + (size_t)(k0 + bk + i) * GG + cb + bc);
        bv[0][i] = f2bf(f.x); bv[1][i] = f2bf(f.y);
        bv[2][i] = f2bf(f.z); bv[3][i] = f2bf(f.w);
      }
#pragma unroll
      for (int j = 0; j < 4; ++j) {
        u16x4v w; w[0] = bv[j][0]; w[1] = bv[j][1]; w[2] = bv[j][2]; w[3] = bv[j][3];
        *reinterpret_cast<u16x4v*>(&Bs[(bc + j) * LDT + bk]) = w;
      }
    }
    __syncthreads();
    bf16x8 af[4], bfr[4];
#pragma unroll
    for (int m = 0; m < 4; ++m)
      af[m] = *reinterpret_cast<const bf16x8*>(&As[(wr + m * 16 + lr) * LDT + lk]);
#pragma unroll
    for (int n = 0; n < 4; ++n)
      bfr[n] = *reinterpret_cast<const bf16x8*>(&Bs[(wc + n * 16 + lr) * LDT + lk]);
#pragma unroll
    for (int m = 0; m < 4; ++m)
#pragma unroll
      for (int n = 0; n < 4; ++n)
        acc[m][n] = __builtin_amdgcn_mfma_f32_16x16x32_bf16(af[m], bfr[n], acc[m][n], 0, 0, 0);
    __syncthreads();
  }
  const int r0 = rb * BM + wr + ((lane >> 4) << 2);
#pragma unroll
  for (int m = 0; m < 4; ++m) {
    int sm[4];
#pragma unroll
    for (int v = 0; v < 4; ++v) sm[v] = perm[r0 + m * 16 + v];
#pragma unroll
    for (int n = 0; n < 4; ++n) {
      const int col = cb + wc + n * 16 + lr;
      const float bias = b2[e * GG + col];
#pragma unroll
      for (int v = 0; v < 4; ++v)
        if (sm[v] >= 0) outg[(size_t)sm[v] * GG + col] = acc[m][n][v] + bias;
    }
  }
}

__global__ __launch_bounds__(256) void immune_k(
    const int* __restrict__ hdr, const int* __restrict__ perm,
    const unsigned short* __restrict__ H1, const float* __restrict__ W2,
    const float* __restrict__ b2, float* __restrict__ out) {
  immune_body(blockIdx.x, hdr, perm, H1, W2, b2, out);
}

__global__ void copy_vt(const float4* __restrict__ v, const float4* __restrict__ t,
                        float4* __restrict__ ov, float4* __restrict__ ot) {
  copy_body(blockIdx.x, v, t, ov, ot);
}

// ================= host ======================================================
extern "C" void kernel_launch(void* const* d_in, const int* in_sizes, int n_in,
                              void* d_out, int out_size, void* d_ws, size_t ws_size,
                              hipStream_t stream) {
  (void)in_sizes; (void)n_in; (void)out_size;
  const float* vis = (const float*)d_in[0];
  const float* txt = (const float*)d_in[1];
  const float* W1i = (const float*)d_in[2];
  const float* b1i = (const float*)d_in[3];
  const float* W2i = (const float*)d_in[4];
  const float* b2i = (const float*)d_in[5];
  const float* W1g = (const float*)d_in[6];
  const float* b1g = (const float*)d_in[7];
  const float* W2g = (const float*)d_in[8];
  const float* b2g = (const float*)d_in[9];
  const int* organ = (const int*)d_in[10];

  float* out_imm = (float*)d_out;
  float* out_gene = out_imm + B_N;
  float* out_vis = out_gene + (size_t)B_N * GG;
  float* out_txt = out_vis + (size_t)B_N * DV;

  int* hdr = (int*)d_ws;
  int* perm = hdr + 128;

  const size_t OFF_ABUF = 32768;
  const size_t OFF_H1 = OFF_ABUF + (size_t)PERM_N * DD * 2;
  const size_t OFF_H2 = OFF_H1 + (size_t)PERM_N * HH * 2;
  const size_t OFF_W1I = OFF_H2 + (size_t)PERM_N * HH * 2;
  const size_t OFF_W1G = OFF_W1I + (size_t)EE * HH * DD * 2;
  const size_t OFF_W2G = OFF_W1G + (size_t)EE * HH * DD * 2;
  const size_t NEED = OFF_W2G + (size_t)EE * GG * HH * 2;

  routing<<<1, 1024, 0, stream>>>(organ, hdr, perm);

  if (ws_size >= NEED) {
    unsigned short* Abuf = (unsigned short*)((char*)d_ws + OFF_ABUF);
    unsigned short* H1 = (unsigned short*)((char*)d_ws + OFF_H1);
    unsigned short* H2 = (unsigned short*)((char*)d_ws + OFF_H2);
    unsigned short* W1i_t = (unsigned short*)((char*)d_ws + OFF_W1I);
    unsigned short* W1g_t = (unsigned short*)((char*)d_ws + OFF_W1G);
    unsigned short* W2g_t = (unsigned short*)((char*)d_ws + OFF_W2G);

    k_prep<<<G_CVT1 * 2 + G_AB, 256, 0, stream>>>(W1i, W1g, W1i_t, W1g_t, vis,
                                                  txt, hdr, perm, Abuf);
    k_main1<<<G_L1 + G_CVT2 + G_COPY, 256, 0, stream>>>(
        Abuf, W1i_t, W1g_t, b1i, b1g, hdr, H1, H2, W2g, W2g_t,
        (const float4*)vis, (const float4*)txt, (float4*)out_vis,
        (float4*)out_txt);
    k_main2<<<G_L2 + G_IMM, 256, 0, stream>>>(H2, W2g_t, b2g, hdr, perm,
                                              out_gene, H1, W2i, b2i, out_imm);
  } else {
    unsigned short* H1 = (unsigned short*)((char*)d_ws + 32768);
    unsigned short* H2 = H1 + (size_t)PERM_N * HH;
    gemm_l1_v0<<<dim3(MAXRB, HH / 128), 256, 0, stream>>>(vis, txt, W1i, b1i, hdr, perm, H1);
    gemm_l1_v0<<<dim3(MAXRB, HH / 128), 256, 0, stream>>>(vis, txt, W1g, b1g, hdr, perm, H2);
    immune_k<<<PERM_N / 4, 256, 0, stream>>>(hdr, perm, H1, W2i, b2i, out_imm);
    gemm_l2_v0<<<dim3(MAXRB, GG / 128), 256, 0, stream>>>(H2, W2g, b2g, hdr, perm, out_gene);
    copy_vt<<<G_COPY, 256, 0, stream>>>((const float4*)vis, (const float4*)txt,
                                        (float4*)out_vis, (float4*)out_txt);
  }
}